// Round 1
// baseline (268.107 us; speedup 1.0000x reference)
//
#include <hip/hip_runtime.h>

#define NBINS 256
#define BLOCK 256                     // 4 waves/block
#define CNT_DW (64 * BLOCK)           // dword (bin>>2)*256 + tid -> bank = tid&31 (2-way, free)
#define BIN_SCALE (256.0f / 255.0f)   // torch.histc width=(255-0)/256; idx=floor(x/width)
#define TARGET_G 1024                 // 2 blocks/CU resident (64KB LDS), 2 generations
#define MAX_PER_THREAD 240            // byte-counter overflow guard

__global__ void zero_out(float* __restrict__ out) {
    const int i = blockIdx.x * blockDim.x + threadIdx.x;
    if (i < 2 * NBINS) out[i] = 0.0f;
}

// element -> (thread-private counter dword, packed byte increment); OOR -> inc=0
__device__ __forceinline__ void classify(float v, int t, int& dw, unsigned& inc) {
    int idx = (int)(v * BIN_SCALE);          // trunc == floor for v>=0
    idx = idx < 255 ? idx : 255;             // x==255 -> last bin
    const bool ok = (v >= 0.0f) && (v <= 255.0f);
    dw = ok ? ((((unsigned)idx >> 2) << 8) + t) : t;
    inc = ok ? (1u << ((idx & 3) << 3)) : 0u;
}

__global__ __launch_bounds__(BLOCK) void hist_kernel(const float* __restrict__ x,
                                                     float* __restrict__ out,
                                                     int n, int G) {
    __shared__ unsigned int cnt[CNT_DW];     // 64 KB: thread-private byte counters
    const int t = threadIdx.x;

    {
        uint4* z4 = (uint4*)cnt;
#pragma unroll
        for (int i = 0; i < CNT_DW / 4 / BLOCK; ++i)
            z4[t + i * BLOCK] = make_uint4(0u, 0u, 0u, 0u);
    }
    __syncthreads();

    const int n4 = n >> 2;
    const float4* __restrict__ x4 = (const float4*)x;
    const int S = G * BLOCK;
    const int i0 = blockIdx.x * BLOCK + t;
    const int K = (i0 < n4) ? ((n4 - i0 + S - 1) / S) : 0;  // my f4 count (grid-stride)

    // DS pipeline state: previous group's (dword, inc, old-value)
    int pd0 = t, pd1 = t, pd2 = t, pd3 = t;
    unsigned ps0 = 0, ps1 = 0, ps2 = 0, ps3 = 0;
    unsigned po0 = 0, po1 = 0, po2 = 0, po3 = 0;
    bool have_p = false;

    auto process = [&](const float4& v) {
        int d0, d1, d2, d3; unsigned s0, s1, s2, s3;
        classify(v.x, t, d0, s0);
        classify(v.y, t, d1, s1);
        classify(v.z, t, d2, s2);
        classify(v.w, t, d3, s3);
        // merge + write previous group (lgkm wait lands here, behind classify)
        unsigned w0 = po0 + ps0;
        unsigned w1 = po1 + ps1 + (pd1 == pd0 ? ps0 : 0u);
        unsigned w2 = po2 + ps2 + (pd2 == pd0 ? ps0 : 0u) + (pd2 == pd1 ? ps1 : 0u);
        unsigned w3 = po3 + ps3 + (pd3 == pd0 ? ps0 : 0u) + (pd3 == pd1 ? ps1 : 0u)
                                + (pd3 == pd2 ? ps2 : 0u);
        cnt[pd0] = w0; cnt[pd1] = w1; cnt[pd2] = w2; cnt[pd3] = w3;
        // this group's reads AFTER previous writes (DS in-order per wave -> RAW safe)
        po0 = cnt[d0]; po1 = cnt[d1]; po2 = cnt[d2]; po3 = cnt[d3];
        pd0 = d0; pd1 = d1; pd2 = d2; pd3 = d3;
        ps0 = s0; ps1 = s1; ps2 = s2; ps3 = s3;
    };

    if (K > 0) {
        have_p = true;
        // peel iter 0: classify + initial reads (first "previous write" is a
        // benign re-write of slot t with +0 since ps*=0, po*=cnt[t])
        float4 A = x4[i0];
        process(A);

        if (K >= 3) {
            // distance-2 prefetch, unroll-2, named regs only (no scratch!)
            float4 B = x4[i0 + S];
            float4 C = x4[i0 + 2 * S];
            int k = 1;
            for (; k + 1 < K; k += 2) {
                float4 nb = x4[i0 + (k + 2 < K ? (k + 2) : 0) * S];
                process(B);                           // iter k
                float4 nc = x4[i0 + (k + 3 < K ? (k + 3) : 0) * S];
                process(C);                           // iter k+1
                B = nb; C = nc;
            }
            if (k < K) process(B);                    // leftover (K even)
        } else {
            for (int k = 1; k < K; ++k) {
                float4 B = x4[i0 + k * S];
                process(B);
            }
        }
    }
    // drain pipeline
    if (have_p) {
        unsigned w0 = po0 + ps0;
        unsigned w1 = po1 + ps1 + (pd1 == pd0 ? ps0 : 0u);
        unsigned w2 = po2 + ps2 + (pd2 == pd0 ? ps0 : 0u) + (pd2 == pd1 ? ps1 : 0u);
        unsigned w3 = po3 + ps3 + (pd3 == pd0 ? ps0 : 0u) + (pd3 == pd1 ? ps1 : 0u)
                                + (pd3 == pd2 ? ps2 : 0u);
        cnt[pd0] = w0; cnt[pd1] = w1; cnt[pd2] = w2; cnt[pd3] = w3;
    }

    // scalar remainder (n % 4)
    for (int j = (n4 << 2) + i0; j < n; j += S) {
        int d; unsigned s;
        classify(x[j], t, d, s);
        cnt[d] += s;
    }
    __syncthreads();

    // Epilogue: thread t -> quad q=t>>2, part p=t&3 sums 64 slices (rotated,
    // conflict-free: bank = ((j+t)&63)&31, distinct pairs across the wave).
    const int q = t >> 2;
    const int p = t & 3;
    unsigned accA = 0, accB = 0;   // packed u16 pairs: bytes{0,2} / bytes{1,3}
#pragma unroll 16
    for (int j = 0; j < 64; ++j) {
        unsigned u = cnt[(q << 8) + (p << 6) + ((j + t) & 63)];
        accA += u & 0x00FF00FFu;
        accB += (u >> 8) & 0x00FF00FFu;
    }
    // combine the 4 parts (consecutive lanes) via wave shuffles
    accA += __shfl_xor(accA, 1, 64);
    accA += __shfl_xor(accA, 2, 64);
    accB += __shfl_xor(accB, 1, 64);
    accB += __shfl_xor(accB, 2, 64);

    if (p == 0) {
        const unsigned b0 = accA & 0xFFFFu, b2 = accA >> 16;
        const unsigned b1 = accB & 0xFFFFu, b3 = accB >> 16;
        // Direct device atomics: exact (integer-valued floats, per-bin totals << 2^24).
        // 1024 blocks x 256 bins = 262K atomics over 256 addresses -> ~5-7 us.
        if (b0) atomicAdd(&out[4 * q + 0], (float)b0);
        if (b1) atomicAdd(&out[4 * q + 1], (float)b1);
        if (b2) atomicAdd(&out[4 * q + 2], (float)b2);
        if (b3) atomicAdd(&out[4 * q + 3], (float)b3);
    }
}

__global__ void count_kernel(const void* __restrict__ bs_raw,
                             float* __restrict__ out) {
    const int as_int = *(const int*)bs_raw;
    float bs;
    if (as_int >= 1 && as_int < (1 << 20)) {
        bs = (float)as_int;
    } else {
        bs = *(const float*)bs_raw;
    }
    out[NBINS + threadIdx.x] = bs * out[0];
}

extern "C" void kernel_launch(void* const* d_in, const int* in_sizes, int n_in,
                              void* d_out, int out_size, void* d_ws, size_t ws_size,
                              hipStream_t stream) {
    const void* bs_ptr;
    const float* x;
    int n;
    if (n_in >= 2 && in_sizes[0] == 1) {
        bs_ptr = d_in[0];
        x = (const float*)d_in[1];
        n = in_sizes[1];
    } else {
        bs_ptr = d_in[1];
        x = (const float*)d_in[0];
        n = in_sizes[0];
    }

    float* out = (float*)d_out;                    // [256 hist | 256 count], float32
    (void)d_ws; (void)ws_size;                     // workspace intentionally UNUSED:
                                                   // avoids the 512 MiB per-iteration
                                                   // harness re-poison fill of d_ws.

    // G: occupancy target, raised if needed so per-thread elements <= MAX_PER_THREAD
    long Gmin = ((long)n + (long)BLOCK * MAX_PER_THREAD - 1) / ((long)BLOCK * MAX_PER_THREAD);
    int G = (int)(Gmin > TARGET_G ? Gmin : TARGET_G);
    if (G < 1) G = 1;

    zero_out<<<2, 256, 0, stream>>>(out);
    hist_kernel<<<G, BLOCK, 0, stream>>>(x, out, n, G);
    count_kernel<<<1, NBINS, 0, stream>>>(bs_ptr, out);
}

// Round 2
// 196.860 us; speedup vs baseline: 1.3619x; 1.3619x over previous
//
#include <hip/hip_runtime.h>

#define NBINS 256
#define BLOCK 256                     // 4 waves/block
#define WAVES (BLOCK / 64)
#define BIN_SCALE (256.0f / 255.0f)   // torch.histc width=(255-0)/256; idx=floor(x/width)
#define GRID 2048                     // 8 blocks/CU * 256 CU -> 32 waves/CU (occupancy cap)

__global__ void zero_out(float* __restrict__ out) {
    const int i = blockIdx.x * blockDim.x + threadIdx.x;
    if (i < 2 * NBINS) out[i] = 0.0f;
}

// torch.histc semantics: idx = floor(x / ((255-0)/256)); x==255 -> last bin; OOR dropped.
__device__ __forceinline__ void bump(float v, unsigned* __restrict__ hw) {
    int idx = (int)(v * BIN_SCALE);          // trunc == floor for v >= 0
    idx = idx < 255 ? idx : 255;
    if (v >= 0.0f && v <= 255.0f)
        atomicAdd(&hw[idx], 1u);             // ds_add_u32: no return -> no dep chain
}

__global__ __launch_bounds__(BLOCK, 8) void hist_kernel(const float* __restrict__ x,
                                                        unsigned int* __restrict__ partial,
                                                        float* __restrict__ out,
                                                        int n, int G, int use_ws) {
    // Per-wave u32 histograms: 4 KB LDS total (was 64 KB byte-counter scheme).
    // ds_add removes the ds_write->ds_read RMW latency chain; occupancy 2->8 blocks/CU.
    __shared__ unsigned int h[WAVES][NBINS];
    const int t = threadIdx.x;
    unsigned* __restrict__ hw = h[t >> 6];

#pragma unroll
    for (int i = t; i < WAVES * NBINS; i += BLOCK) ((unsigned*)h)[i] = 0u;
    __syncthreads();

    const int n4 = n >> 2;
    const float4* __restrict__ x4 = (const float4*)x;
    const int S = G * BLOCK;
    const int i0 = blockIdx.x * BLOCK + t;

    // Main loop: coalesced float4 loads, 4 LDS atomics each. No cross-iteration
    // dependency -> compiler hoists next load over this iter's ds_adds; 8 waves/SIMD
    // of TLP hide HBM latency.
    for (int i = i0; i < n4; i += S) {
        const float4 v = x4[i];
        bump(v.x, hw);
        bump(v.y, hw);
        bump(v.z, hw);
        bump(v.w, hw);
    }
    // scalar remainder (n % 4)
    for (int j = (n4 << 2) + i0; j < n; j += S)
        bump(x[j], hw);

    __syncthreads();

    // Merge 4 wave-histograms; bank = t&31, conflict-free.
    unsigned s = h[0][t] + h[1][t] + h[2][t] + h[3][t];
    if (use_ws) {
        partial[(size_t)blockIdx.x * NBINS + t] = s;   // coalesced 1 KB store
    } else if (s) {
        atomicAdd(&out[t], (float)s);                  // fallback only (slow path)
    }
}

// 256 blocks; block j sums a g-slice (coalesced 1 KB row reads), <=256 atomics/bin total.
__global__ __launch_bounds__(NBINS) void reduce_kernel(const unsigned int* __restrict__ partial,
                                                       float* __restrict__ out,
                                                       int G, int slice) {
    const int bin = threadIdx.x;
    const int g0 = blockIdx.x * slice;
    const int g1 = (g0 + slice < G) ? (g0 + slice) : G;
    unsigned s = 0;
    for (int g = g0; g < g1; ++g)
        s += partial[(size_t)g * NBINS + bin];
    if (s) atomicAdd(&out[bin], (float)s);   // exact: integer counts < 2^24
}

__global__ void count_kernel(const void* __restrict__ bs_raw,
                             float* __restrict__ out) {
    const int as_int = *(const int*)bs_raw;
    float bs;
    if (as_int >= 1 && as_int < (1 << 20)) {
        bs = (float)as_int;
    } else {
        bs = *(const float*)bs_raw;
    }
    out[NBINS + threadIdx.x] = bs * out[0];
}

extern "C" void kernel_launch(void* const* d_in, const int* in_sizes, int n_in,
                              void* d_out, int out_size, void* d_ws, size_t ws_size,
                              hipStream_t stream) {
    const void* bs_ptr;
    const float* x;
    int n;
    if (n_in >= 2 && in_sizes[0] == 1) {
        bs_ptr = d_in[0];
        x = (const float*)d_in[1];
        n = in_sizes[1];
    } else {
        bs_ptr = d_in[1];
        x = (const float*)d_in[0];
        n = in_sizes[0];
    }

    float* out = (float*)d_out;                    // [256 hist | 256 count], float32
    unsigned int* partial = (unsigned int*)d_ws;   // [G][256] u32 partials

    const int G = GRID;                            // grid-stride covers any n
    const size_t ws_need = (size_t)G * NBINS * sizeof(unsigned int);   // 2 MB
    const int use_ws = (ws_size >= ws_need) ? 1 : 0;

    zero_out<<<2, 256, 0, stream>>>(out);
    hist_kernel<<<G, BLOCK, 0, stream>>>(x, partial, out, n, G, use_ws);
    if (use_ws) {
        const int slice = (G + NBINS - 1) / NBINS;
        reduce_kernel<<<NBINS, NBINS, 0, stream>>>(partial, out, G, slice);
    }
    count_kernel<<<1, NBINS, 0, stream>>>(bs_ptr, out);
}

// Round 3
// 195.067 us; speedup vs baseline: 1.3744x; 1.0092x over previous
//
#include <hip/hip_runtime.h>

#define NBINS 256
#define BLOCK 256                     // 4 waves/block
#define WAVES (BLOCK / 64)
#define BIN_SCALE (256.0f / 255.0f)   // torch.histc width=(255-0)/256; idx=floor(x/width)
#define GRID 2048                     // 8 blocks/CU * 256 CU -> 32 waves/CU (occupancy cap)

// ---- fallback-only helpers (workspace too small; not expected in practice) ----
__global__ void zero_out(float* __restrict__ out) {
    const int i = blockIdx.x * blockDim.x + threadIdx.x;
    if (i < 2 * NBINS) out[i] = 0.0f;
}
__global__ void count_kernel(const void* __restrict__ bs_raw,
                             float* __restrict__ out) {
    const int as_int = *(const int*)bs_raw;
    float bs = (as_int >= 1 && as_int < (1 << 20)) ? (float)as_int : *(const float*)bs_raw;
    out[NBINS + threadIdx.x] = bs * out[0];
}

// torch.histc semantics: idx = floor(x / ((255-0)/256)); x==255 -> last bin; OOR dropped.
__device__ __forceinline__ void bump(float v, unsigned* __restrict__ hw) {
    int idx = (int)(v * BIN_SCALE);          // trunc == floor for v >= 0
    idx = idx < 255 ? idx : 255;
    if (v >= 0.0f && v <= 255.0f)
        atomicAdd(&hw[idx], 1u);             // ds_add_u32: no return -> no dep chain
}

__global__ __launch_bounds__(BLOCK, 8) void hist_kernel(const float* __restrict__ x,
                                                        unsigned int* __restrict__ partial,
                                                        float* __restrict__ out,
                                                        int n, int G, int use_ws) {
    // Per-wave u32 histograms: 4 KB LDS; ds_add has no RMW dep chain; 8 blocks/CU.
    __shared__ unsigned int h[WAVES][NBINS];
    const int t = threadIdx.x;
    unsigned* __restrict__ hw = h[t >> 6];

#pragma unroll
    for (int i = t; i < WAVES * NBINS; i += BLOCK) ((unsigned*)h)[i] = 0u;
    __syncthreads();

    const int n4 = n >> 2;
    const float4* __restrict__ x4 = (const float4*)x;
    const int S = G * BLOCK;
    const int i0 = blockIdx.x * BLOCK + t;

    // Unroll-2: both float4 loads issue before any ds_add -> 2 KB in flight per wave
    // (32 waves/CU * 2 KB covers the ~22 KB latency-BW product per CU).
    int i = i0;
    for (; i + S < n4; i += 2 * S) {
        const float4 a = x4[i];
        const float4 b = x4[i + S];
        bump(a.x, hw); bump(a.y, hw); bump(a.z, hw); bump(a.w, hw);
        bump(b.x, hw); bump(b.y, hw); bump(b.z, hw); bump(b.w, hw);
    }
    if (i < n4) {
        const float4 a = x4[i];
        bump(a.x, hw); bump(a.y, hw); bump(a.z, hw); bump(a.w, hw);
    }
    // scalar remainder (n % 4)
    for (int j = (n4 << 2) + i0; j < n; j += S)
        bump(x[j], hw);

    __syncthreads();

    // Merge 4 wave-histograms; bank = t&31, conflict-free.
    unsigned s = h[0][t] + h[1][t] + h[2][t] + h[3][t];
    if (use_ws) {
        partial[(size_t)blockIdx.x * NBINS + t] = s;   // coalesced 1 KB store
    } else if (s) {
        atomicAdd(&out[t], (float)s);                  // fallback (needs zero_out)
    }
}

// Fused reduce + count: one block per bin, direct write (no atomics, no pre-zero).
// Column reads of `partial` are uncoalesced but L2/L3-resident (2 MB just written).
// Block 0 additionally writes the 256-wide count = bs * hist[0].
__global__ __launch_bounds__(NBINS) void reduce_count_kernel(const unsigned int* __restrict__ partial,
                                                             const void* __restrict__ bs_raw,
                                                             float* __restrict__ out,
                                                             int G) {
    const int bin = blockIdx.x;
    const int t = threadIdx.x;

    unsigned s = 0;
    for (int g = t; g < G; g += NBINS)
        s += partial[(size_t)g * NBINS + bin];

    // wave reduce (64 lanes)
    s += __shfl_xor(s, 1, 64);
    s += __shfl_xor(s, 2, 64);
    s += __shfl_xor(s, 4, 64);
    s += __shfl_xor(s, 8, 64);
    s += __shfl_xor(s, 16, 64);
    s += __shfl_xor(s, 32, 64);

    // cross-wave reduce via LDS
    __shared__ unsigned wsum[WAVES];
    __shared__ unsigned total_sh;
    if ((t & 63) == 0) wsum[t >> 6] = s;
    __syncthreads();
    if (t == 0) {
        unsigned total = 0;
#pragma unroll
        for (int w = 0; w < WAVES; ++w) total += wsum[w];
        total_sh = total;
        out[bin] = (float)total;               // exact: integer counts < 2^24
    }
    if (bin == 0) {
        __syncthreads();
        const int as_int = *(const int*)bs_raw;
        float bs = (as_int >= 1 && as_int < (1 << 20)) ? (float)as_int
                                                       : *(const float*)bs_raw;
        out[NBINS + t] = bs * (float)total_sh;
    }
}

extern "C" void kernel_launch(void* const* d_in, const int* in_sizes, int n_in,
                              void* d_out, int out_size, void* d_ws, size_t ws_size,
                              hipStream_t stream) {
    const void* bs_ptr;
    const float* x;
    int n;
    if (n_in >= 2 && in_sizes[0] == 1) {
        bs_ptr = d_in[0];
        x = (const float*)d_in[1];
        n = in_sizes[1];
    } else {
        bs_ptr = d_in[1];
        x = (const float*)d_in[0];
        n = in_sizes[0];
    }

    float* out = (float*)d_out;                    // [256 hist | 256 count], float32
    unsigned int* partial = (unsigned int*)d_ws;   // [G][256] u32 partials

    const int G = GRID;                            // grid-stride covers any n
    const size_t ws_need = (size_t)G * NBINS * sizeof(unsigned int);   // 2 MB
    const int use_ws = (ws_size >= ws_need) ? 1 : 0;

    if (use_ws) {
        hist_kernel<<<G, BLOCK, 0, stream>>>(x, partial, out, n, G, 1);
        reduce_count_kernel<<<NBINS, NBINS, 0, stream>>>(partial, bs_ptr, out, G);
    } else {
        zero_out<<<2, 256, 0, stream>>>(out);
        hist_kernel<<<G, BLOCK, 0, stream>>>(x, partial, out, n, G, 0);
        count_kernel<<<1, NBINS, 0, stream>>>(bs_ptr, out);
    }
}